// Round 12
// baseline (321.729 us; speedup 1.0000x reference)
//
#include <hip/hip_runtime.h>
#include <hip/hip_bf16.h>
#include <stdint.h>

// Problem constants
#define BB 4
#define LL 4096
#define DD 1024
#define HH 16
#define WW 128
#define DH 64
#define NWIN 32            // LL / WW
#define MTOT (BB*LL)       // 16384
#define NQKV (3*DD)        // 3072

typedef short bf16x8 __attribute__((ext_vector_type(8)));
typedef float f32x4 __attribute__((ext_vector_type(4)));
typedef unsigned short u16;

__device__ __forceinline__ u16 f2bf(float f) {
    union { float f; uint32_t u; } v; v.f = f;
    uint32_t u = v.u;
    uint32_t r = (u + 0x7fffu + ((u >> 16) & 1u)) >> 16;
    return (u16)r;
}

// async global->LDS, 16 bytes per lane, HW dest = wave-uniform base + lane*16
#define GLOAD_LDS16(gptr, ldsptr)                                                        \
    __builtin_amdgcn_global_load_lds((const __attribute__((address_space(1))) void*)(gptr), \
                                     (__attribute__((address_space(3))) void*)(ldsptr),      \
                                     16, 0, 0)

// ---------------- fp32 -> bf16 conversion (vectorized) ----------------
__global__ __launch_bounds__(256) void cvt_f32_bf16(const float* __restrict__ in,
                                                    u16* __restrict__ out, int n8) {
    int i = blockIdx.x * blockDim.x + threadIdx.x;
    int stride = gridDim.x * blockDim.x;
    for (; i < n8; i += stride) {
        const float4* p = (const float4*)(in + (size_t)i * 8);
        float4 a = p[0], b = p[1];
        bf16x8 o;
        o[0] = (short)f2bf(a.x); o[1] = (short)f2bf(a.y);
        o[2] = (short)f2bf(a.z); o[3] = (short)f2bf(a.w);
        o[4] = (short)f2bf(b.x); o[5] = (short)f2bf(b.y);
        o[6] = (short)f2bf(b.z); o[7] = (short)f2bf(b.w);
        *(bf16x8*)(out + (size_t)i * 8) = o;
    }
}

// =====================================================================
// 256x128 tile, BK=32, K=1024 (32 K-tiles), 512 threads = 8 waves (4M x 2N),
// wave tile 64x64, acc[4][4] (64 regs). LDS: 2 slots x 24 KB = 48 KB ->
// TWO blocks resident per CU (16 waves, 4/SIMD) — m114 inter-block
// overlap hides barrier/drain stalls (the m97 mechanism, at 2x the tile).
//
// Depth-1 pipeline, ONE barrier per K-tile:
//   { stage(j+1 -> other slot); 8 ds_reads + 16 MFMA (tile j);
//     lgkmcnt(0); vmcnt(0); barrier }
// vmcnt(0) waits on loads issued a full compute phase earlier (cheap);
// the pre-barrier placement makes the drain guarantee collective ->
// race-free (each wave's stage lands before any wave crosses the barrier).
// Slot j+1 was last read at tile j-1, whose reads completed before the
// tile j-1 barrier -> no overwrite race.
//
// Slot layout: A-unit0 rows 0-127 @0, A-unit1 rows 128-255 @8192,
// B rows 0-127 @16384 (each [128r][32k] bf16, XOR-swizzled as verified
// in R4-R9: physical = r*64 + ((g ^ ((r>>1)&3))<<4); gload_lds dest
// linear with inverse-swizzled per-lane global source).
// =====================================================================

#define BARR   __builtin_amdgcn_s_barrier()
#define LGKM0  asm volatile("s_waitcnt lgkmcnt(0)" ::: "memory")
#define VM0    asm volatile("s_waitcnt vmcnt(0)" ::: "memory")
#define RD(p)  (*(const bf16x8*)(p))

// Bijective XCD-chunked block swizzle; col-major (by fast -> shared B panel).
__device__ __forceinline__ void map_block(int& bx, int& by) {
    int nwg = gridDim.x;             // multiple of 8
    int wg  = blockIdx.x;
    int chunk = nwg >> 3;
    int sw = (wg & 7) * chunk + (wg >> 3);
    by = sw & 63;                    // 64 M-tiles (BM=256)
    bx = sw >> 6;
}

// Core: computes acc[4][4] for this block/wave. A:[M][1024], Bw:[N][1024] bf16.
__device__ __forceinline__ void gemm256x128_core(const u16* __restrict__ A,
                                                 const u16* __restrict__ Bw,
                                                 int row0, int col0,
                                                 char* lds, f32x4 acc[4][4]) {
    const int tid  = threadIdx.x;
    const int lane = tid & 63;
    const int wave = tid >> 6;           // 0..7
    const int wm   = wave >> 1;          // 0..3  (M sub-tile of 64)
    const int wn   = wave & 1;           // 0..1  (N sub-tile of 64)
    const int colb = lane & 15;
    const int kgrp = lane >> 4;          // 0..3

    // fragment-read byte offsets within a slot (XOR-swizzled layout)
    const int swz  = (kgrp ^ ((colb >> 1) & 3)) << 4;
    const int aoff = (wm >> 1) * 8192 + ((wm & 1) * 64 + colb) * 64 + swz;
    const int boff = 16384 + (wn * 64 + colb) * 64 + swz;

    // stage source mapping (inverse swizzle): 3 gloads per thread per tile
    const int lrow  = tid >> 2;                               // 0..127
    const int lkoff = ((tid & 3) ^ ((tid >> 3) & 3)) * 8;     // swizzled k-elems
    const u16* asrc0 = A  + (size_t)(row0 + lrow) * 1024 + lkoff;
    const u16* asrc1 = A  + (size_t)(row0 + 128 + lrow) * 1024 + lkoff;
    const u16* bsrc  = Bw + (size_t)(col0 + lrow) * 1024 + lkoff;

    #pragma unroll
    for (int m = 0; m < 4; ++m)
        #pragma unroll
        for (int n = 0; n < 4; ++n)
            acc[m][n] = (f32x4){0.f, 0.f, 0.f, 0.f};

    // prologue: stage tile 0 into slot 0, force landed, publish
    GLOAD_LDS16(asrc0, lds + wave * 1024);
    GLOAD_LDS16(asrc1, lds + 8192 + wave * 1024);
    GLOAD_LDS16(bsrc,  lds + 16384 + wave * 1024);
    VM0;
    BARR;

    #pragma unroll 2
    for (int j = 0; j < 32; ++j) {
        char* sb = lds + (j & 1) * 24576;
        if (j < 31) {
            char* db = lds + ((j + 1) & 1) * 24576;
            GLOAD_LDS16(asrc0 + (size_t)(j + 1) * 32, db + wave * 1024);
            GLOAD_LDS16(asrc1 + (size_t)(j + 1) * 32, db + 8192 + wave * 1024);
            GLOAD_LDS16(bsrc  + (size_t)(j + 1) * 32, db + 16384 + wave * 1024);
        }
        bf16x8 a0 = RD(sb + aoff);
        bf16x8 a1 = RD(sb + aoff + 1024);
        bf16x8 a2 = RD(sb + aoff + 2048);
        bf16x8 a3 = RD(sb + aoff + 3072);
        bf16x8 b0 = RD(sb + boff);
        bf16x8 b1 = RD(sb + boff + 1024);
        bf16x8 b2 = RD(sb + boff + 2048);
        bf16x8 b3 = RD(sb + boff + 3072);
        acc[0][0] = __builtin_amdgcn_mfma_f32_16x16x32_bf16(a0, b0, acc[0][0], 0,0,0);
        acc[1][0] = __builtin_amdgcn_mfma_f32_16x16x32_bf16(a1, b0, acc[1][0], 0,0,0);
        acc[2][0] = __builtin_amdgcn_mfma_f32_16x16x32_bf16(a2, b0, acc[2][0], 0,0,0);
        acc[3][0] = __builtin_amdgcn_mfma_f32_16x16x32_bf16(a3, b0, acc[3][0], 0,0,0);
        acc[0][1] = __builtin_amdgcn_mfma_f32_16x16x32_bf16(a0, b1, acc[0][1], 0,0,0);
        acc[1][1] = __builtin_amdgcn_mfma_f32_16x16x32_bf16(a1, b1, acc[1][1], 0,0,0);
        acc[2][1] = __builtin_amdgcn_mfma_f32_16x16x32_bf16(a2, b1, acc[2][1], 0,0,0);
        acc[3][1] = __builtin_amdgcn_mfma_f32_16x16x32_bf16(a3, b1, acc[3][1], 0,0,0);
        acc[0][2] = __builtin_amdgcn_mfma_f32_16x16x32_bf16(a0, b2, acc[0][2], 0,0,0);
        acc[1][2] = __builtin_amdgcn_mfma_f32_16x16x32_bf16(a1, b2, acc[1][2], 0,0,0);
        acc[2][2] = __builtin_amdgcn_mfma_f32_16x16x32_bf16(a2, b2, acc[2][2], 0,0,0);
        acc[3][2] = __builtin_amdgcn_mfma_f32_16x16x32_bf16(a3, b2, acc[3][2], 0,0,0);
        acc[0][3] = __builtin_amdgcn_mfma_f32_16x16x32_bf16(a0, b3, acc[0][3], 0,0,0);
        acc[1][3] = __builtin_amdgcn_mfma_f32_16x16x32_bf16(a1, b3, acc[1][3], 0,0,0);
        acc[2][3] = __builtin_amdgcn_mfma_f32_16x16x32_bf16(a2, b3, acc[2][3], 0,0,0);
        acc[3][3] = __builtin_amdgcn_mfma_f32_16x16x32_bf16(a3, b3, acc[3][3], 0,0,0);
        if (j < 31) {
            LGKM0;      // my slot-j reads done (slot j re-staged next tile)
            VM0;        // my tile-j+1 stages landed (issued a full phase ago)
            BARR;       // publish both guarantees collectively
        }
    }
}

// ---------------- Kernel 1: QKV GEMM + bias + scatter to windowed q/k/vT ----------------
__global__ __launch_bounds__(512, 4) void qkv_gemm_kernel(const u16* __restrict__ xb,
                                                          const u16* __restrict__ wb,
                                                          const float* __restrict__ bias,
                                                          u16* __restrict__ qd,
                                                          u16* __restrict__ kd,
                                                          u16* __restrict__ vtd) {
    __shared__ char g_lds[49152];
    f32x4 acc[4][4];
    int bx, by;
    map_block(bx, by);
    const int row0 = by * 256;
    const int col0 = bx * 128;
    gemm256x128_core(xb, wb, row0, col0, g_lds, acc);

    const int lane = threadIdx.x & 63;
    const int wave = threadIdx.x >> 6;
    const int wm = wave >> 1, wn = wave & 1;
    const int colb = lane & 15;
    const int rgrp = lane >> 4;

    #pragma unroll
    for (int m = 0; m < 4; ++m) {
        #pragma unroll
        for (int n = 0; n < 4; ++n) {
            #pragma unroll
            for (int j = 0; j < 4; ++j) {
                int gm = row0 + wm * 64 + m * 16 + rgrp * 4 + j;
                int gn = col0 + wn * 64 + n * 16 + colb;
                float v = acc[m][n][j] + bias[gn];
                int which = gn >> 10, c = gn & 1023, h = c >> 6, d = c & 63;
                int b = gm >> 12, l = gm & 4095, n0 = l >> 7, wq = l & 127;
                size_t wbase = (size_t)((b * HH + h) * NWIN + n0) * (WW * DH);
                if (which == 0)      qd [wbase + wq * 64 + d] = f2bf(v * 0.125f);
                else if (which == 1) kd [wbase + wq * 64 + d] = f2bf(v);
                else                 vtd[wbase + d * 128 + wq] = f2bf(v);
            }
        }
    }
}

// ---------------- Kernel 3: output projection GEMM + bias -> fp32 out ----------------
__global__ __launch_bounds__(512, 4) void out_gemm_kernel(const u16* __restrict__ ab,
                                                          const u16* __restrict__ wb,
                                                          const float* __restrict__ bias,
                                                          float* __restrict__ out) {
    __shared__ char g_lds[49152];
    f32x4 acc[4][4];
    int bx, by;
    map_block(bx, by);
    const int row0 = by * 256;
    const int col0 = bx * 128;
    gemm256x128_core(ab, wb, row0, col0, g_lds, acc);

    const int lane = threadIdx.x & 63;
    const int wave = threadIdx.x >> 6;
    const int wm = wave >> 1, wn = wave & 1;
    const int colb = lane & 15;
    const int rgrp = lane >> 4;

    #pragma unroll
    for (int m = 0; m < 4; ++m) {
        #pragma unroll
        for (int n = 0; n < 4; ++n) {
            #pragma unroll
            for (int j = 0; j < 4; ++j) {
                int gm = row0 + wm * 64 + m * 16 + rgrp * 4 + j;
                int gn = col0 + wn * 64 + n * 16 + colb;
                out[(size_t)gm * DD + gn] = acc[m][n][j] + bias[gn];
            }
        }
    }
}

// ---------------- Kernel 2: windowed causal attention (unchanged) ----------------
__global__ __launch_bounds__(256) void attn_kernel(const u16* __restrict__ q,
                                                   const u16* __restrict__ k,
                                                   const u16* __restrict__ vt,
                                                   u16* __restrict__ aout) {
    __shared__ u16 Ps[4][32 * 136];

    const int win = blockIdx.x;
    const int b  = win >> 9;
    const int h  = (win >> 5) & 15;
    const int n0 = win & 31;
    const u16* qp = q  + (size_t)win * (WW * DH);
    const u16* kp = k  + (size_t)win * (WW * DH);
    const u16* vp = vt + (size_t)win * (WW * DH);

    const int lane = threadIdx.x & 63;
    const int wave = threadIdx.x >> 6;
    const int wrow = wave * 32;
    const int colb = lane & 15;
    const int kgrp = lane >> 4;
    const int rgrp = kgrp;

    f32x4 s[2][8];
    #pragma unroll
    for (int m = 0; m < 2; ++m)
        #pragma unroll
        for (int n = 0; n < 8; ++n)
            s[m][n] = (f32x4){0.f, 0.f, 0.f, 0.f};

    #pragma unroll
    for (int kk = 0; kk < 2; ++kk) {
        bf16x8 aq[2];
        #pragma unroll
        for (int m = 0; m < 2; ++m)
            aq[m] = *(const bf16x8*)&qp[(wrow + m * 16 + colb) * 64 + kk * 32 + kgrp * 8];
        #pragma unroll
        for (int n = 0; n < 8; ++n) {
            bf16x8 bk = *(const bf16x8*)&kp[(n * 16 + colb) * 64 + kk * 32 + kgrp * 8];
            s[0][n] = __builtin_amdgcn_mfma_f32_16x16x32_bf16(aq[0], bk, s[0][n], 0, 0, 0);
            s[1][n] = __builtin_amdgcn_mfma_f32_16x16x32_bf16(aq[1], bk, s[1][n], 0, 0, 0);
        }
    }

    #pragma unroll
    for (int m = 0; m < 2; ++m) {
        #pragma unroll
        for (int j = 0; j < 4; ++j) {
            int row = wrow + m * 16 + rgrp * 4 + j;
            float vals[8];
            float mx = -1e30f;
            #pragma unroll
            for (int n = 0; n < 8; ++n) {
                int col = n * 16 + colb;
                float v = s[m][n][j];
                if (col > row) v = -1e30f;
                vals[n] = v;
                mx = fmaxf(mx, v);
            }
            #pragma unroll
            for (int off = 1; off < 16; off <<= 1)
                mx = fmaxf(mx, __shfl_xor(mx, off, 64));
            float sum = 0.f;
            #pragma unroll
            for (int n = 0; n < 8; ++n) {
                float p = __expf(vals[n] - mx);
                vals[n] = p;
                sum += p;
            }
            #pragma unroll
            for (int off = 1; off < 16; off <<= 1)
                sum += __shfl_xor(sum, off, 64);
            float r = 1.0f / sum;
            #pragma unroll
            for (int n = 0; n < 8; ++n)
                Ps[wave][(m * 16 + rgrp * 4 + j) * 136 + n * 16 + colb] = f2bf(vals[n] * r);
        }
    }
    __syncthreads();

    f32x4 o[2][4];
    #pragma unroll
    for (int m = 0; m < 2; ++m)
        #pragma unroll
        for (int n = 0; n < 4; ++n)
            o[m][n] = (f32x4){0.f, 0.f, 0.f, 0.f};

    #pragma unroll
    for (int kk = 0; kk < 4; ++kk) {
        bf16x8 ap[2];
        #pragma unroll
        for (int m = 0; m < 2; ++m)
            ap[m] = *(const bf16x8*)&Ps[wave][(m * 16 + colb) * 136 + kk * 32 + kgrp * 8];
        #pragma unroll
        for (int n = 0; n < 4; ++n) {
            bf16x8 bv = *(const bf16x8*)&vp[(n * 16 + colb) * 128 + kk * 32 + kgrp * 8];
            o[0][n] = __builtin_amdgcn_mfma_f32_16x16x32_bf16(ap[0], bv, o[0][n], 0, 0, 0);
            o[1][n] = __builtin_amdgcn_mfma_f32_16x16x32_bf16(ap[1], bv, o[1][n], 0, 0, 0);
        }
    }

    #pragma unroll
    for (int m = 0; m < 2; ++m) {
        #pragma unroll
        for (int n = 0; n < 4; ++n) {
            #pragma unroll
            for (int j = 0; j < 4; ++j) {
                int row = wrow + m * 16 + rgrp * 4 + j;
                int l = n0 * 128 + row;
                int d = h * 64 + n * 16 + colb;
                aout[((size_t)(b * LL + l)) * DD + d] = f2bf(o[m][n][j]);
            }
        }
    }
}

// ---------------- launch ----------------
extern "C" void kernel_launch(void* const* d_in, const int* in_sizes, int n_in,
                              void* d_out, int out_size, void* d_ws, size_t ws_size,
                              hipStream_t stream) {
    const float* x     = (const float*)d_in[0];
    const float* qkv_w = (const float*)d_in[1];
    const float* qkv_b = (const float*)d_in[2];
    const float* out_w = (const float*)d_in[3];
    const float* out_b = (const float*)d_in[4];
    float* out = (float*)d_out;

    char* ws = (char*)d_ws;
    u16* xb   = (u16*)(ws);                           // reused as attn_out
    u16* qwb  = (u16*)(ws + 33554432);
    u16* owb  = (u16*)(ws + 39845888);
    u16* qws  = (u16*)(ws + 41943040);
    u16* kws  = (u16*)(ws + 75497472);
    u16* vtws = (u16*)(ws + 109051904);

    cvt_f32_bf16<<<2048, 256, 0, stream>>>(x, xb, 16777216 / 8);
    cvt_f32_bf16<<<1536, 256, 0, stream>>>(qkv_w, qwb, 3145728 / 8);
    cvt_f32_bf16<<<512, 256, 0, stream>>>(out_w, owb, 1048576 / 8);

    qkv_gemm_kernel<<<(MTOT / 256) * (NQKV / 128), 512, 0, stream>>>(xb, qwb, qkv_b, qws, kws, vtws);

    attn_kernel<<<BB * HH * NWIN, 256, 0, stream>>>(qws, kws, vtws, xb /* attn_out */);

    out_gemm_kernel<<<(MTOT / 256) * (DD / 128), 512, 0, stream>>>(xb, owb, out_b, out);
}

// Round 13
// 303.386 us; speedup vs baseline: 1.0605x; 1.0605x over previous
//
#include <hip/hip_runtime.h>
#include <hip/hip_bf16.h>
#include <stdint.h>

// Problem constants
#define BB 4
#define LL 4096
#define DD 1024
#define HH 16
#define WW 128
#define DH 64
#define NWIN 32            // LL / WW
#define MTOT (BB*LL)       // 16384
#define NQKV (3*DD)        // 3072

typedef short bf16x8 __attribute__((ext_vector_type(8)));
typedef float f32x4 __attribute__((ext_vector_type(4)));
typedef unsigned short u16;

__device__ __forceinline__ u16 f2bf(float f) {
    union { float f; uint32_t u; } v; v.f = f;
    uint32_t u = v.u;
    uint32_t r = (u + 0x7fffu + ((u >> 16) & 1u)) >> 16;
    return (u16)r;
}

// async global->LDS, 16 bytes per lane, HW dest = uniform base + lane*16
#define GLOAD_LDS16(gptr, ldsptr)                                                        \
    __builtin_amdgcn_global_load_lds((const __attribute__((address_space(1))) void*)(gptr), \
                                     (__attribute__((address_space(3))) void*)(ldsptr),      \
                                     16, 0, 0)

// ---------------- fp32 -> bf16 conversion (vectorized) ----------------
__global__ __launch_bounds__(256) void cvt_f32_bf16(const float* __restrict__ in,
                                                    u16* __restrict__ out, int n8) {
    int i = blockIdx.x * blockDim.x + threadIdx.x;
    int stride = gridDim.x * blockDim.x;
    for (; i < n8; i += stride) {
        const float4* p = (const float4*)(in + (size_t)i * 8);
        float4 a = p[0], b = p[1];
        bf16x8 o;
        o[0] = (short)f2bf(a.x); o[1] = (short)f2bf(a.y);
        o[2] = (short)f2bf(a.z); o[3] = (short)f2bf(a.w);
        o[4] = (short)f2bf(b.x); o[5] = (short)f2bf(b.y);
        o[6] = (short)f2bf(b.z); o[7] = (short)f2bf(b.w);
        *(bf16x8*)(out + (size_t)i * 8) = o;
    }
}

// ---------------- shared MFMA GEMM core: 128x128 tile, BK=32, K=1024 ----------------
// R3 (best-known-good, 178us) + ONLY the verified XOR swizzle (single-variable).
// LDS: A[128][32] + B[128][32] bf16 = 16 KB -> high block residency (m114 overlap).
// Swizzle: logical (row r, 16B-slot g) at physical r*64 + ((g ^ ((r>>1)&3))<<4).
//  - gload_lds dest stays LINEAR (chunk c*1024 + lane*16 == r*64 + (l&3)*16);
//    SOURCE carries the inverse: k-elems = ((l&3) ^ ((l>>3)&3))*8
//    ((r>>1)&3 == (l>>3)&3 for both chunks since 8c = 0 mod 4).
//  - frag reads: k-slot = kgrp ^ ((colb>>1)&3) (row = wr+m*16+colb; wr,m terms
//    vanish mod 4 after >>1) -> m-independent, strides unchanged.
// Verified conflict-free (0 SQ_LDS_BANK_CONFLICT) at this unit shape in R4-R9.
__device__ __forceinline__ void gemm_tile_1024(const u16* __restrict__ A,
                                               const u16* __restrict__ Bw,
                                               int row0, int col0,
                                               u16* Als, u16* Bls,
                                               f32x4 acc[4][4]) {
    const int tid  = threadIdx.x;
    const int lane = tid & 63;
    const int wave = tid >> 6;
    const int wr = (wave >> 1) * 64;
    const int wc = (wave & 1) * 64;
    const int colb = lane & 15;
    const int kgrp = lane >> 4;          // 0..3
    const int kswz = (kgrp ^ ((colb >> 1) & 3)) * 8;   // swizzled k-elem offset

    #pragma unroll
    for (int m = 0; m < 4; ++m)
        #pragma unroll
        for (int n = 0; n < 4; ++n)
            acc[m][n] = (f32x4){0.f, 0.f, 0.f, 0.f};

    // staging: wave w fills LDS chunks 2w, 2w+1 of each tile (1 KiB each).
    // chunk c = rows [16c, 16c+16); lane l sources row 16c+(l>>2),
    // swizzled k-elem ((l&3)^((l>>3)&3))*8 -> LDS linear c*1024 + l*16.
    const int c0 = wave * 2, c1 = wave * 2 + 1;
    const int lr = lane >> 2;            // row within chunk
    const int lk = ((lane & 3) ^ ((lane >> 3) & 3)) * 8;   // swizzled source k

    const u16* ga0 = &A [(size_t)(row0 + c0 * 16 + lr) * 1024 + lk];
    const u16* ga1 = &A [(size_t)(row0 + c1 * 16 + lr) * 1024 + lk];
    const u16* gb0 = &Bw[(size_t)(col0 + c0 * 16 + lr) * 1024 + lk];
    const u16* gb1 = &Bw[(size_t)(col0 + c1 * 16 + lr) * 1024 + lk];
    u16* la0 = &Als[c0 * 512];
    u16* la1 = &Als[c1 * 512];
    u16* lb0 = &Bls[c0 * 512];
    u16* lb1 = &Bls[c1 * 512];

    for (int kt = 0; kt < 1024; kt += 32) {
        __syncthreads();                 // prior iteration's LDS reads done
        GLOAD_LDS16(ga0 + kt, la0);
        GLOAD_LDS16(ga1 + kt, la1);
        GLOAD_LDS16(gb0 + kt, lb0);
        GLOAD_LDS16(gb1 + kt, lb1);
        __syncthreads();                 // compiler drains vmcnt before barrier

        bf16x8 af[4], bf[4];
        #pragma unroll
        for (int m = 0; m < 4; ++m)
            af[m] = *(const bf16x8*)&Als[(wr + m * 16 + colb) * 32 + kswz];
        #pragma unroll
        for (int n = 0; n < 4; ++n)
            bf[n] = *(const bf16x8*)&Bls[(wc + n * 16 + colb) * 32 + kswz];
        #pragma unroll
        for (int m = 0; m < 4; ++m)
            #pragma unroll
            for (int n = 0; n < 4; ++n)
                acc[m][n] = __builtin_amdgcn_mfma_f32_16x16x32_bf16(af[m], bf[n], acc[m][n], 0, 0, 0);
    }
}

// ---------------- Kernel 1: QKV GEMM + bias + scatter to windowed q/k/vT ----------------
__global__ __launch_bounds__(256) void qkv_gemm_kernel(const u16* __restrict__ xb,
                                                       const u16* __restrict__ wb,
                                                       const float* __restrict__ bias,
                                                       u16* __restrict__ qd,
                                                       u16* __restrict__ kd,
                                                       u16* __restrict__ vtd) {
    __shared__ u16 Als[128 * 32];
    __shared__ u16 Bls[128 * 32];
    f32x4 acc[4][4];
    const int row0 = blockIdx.y * 128;
    const int col0 = blockIdx.x * 128;
    gemm_tile_1024(xb, wb, row0, col0, Als, Bls, acc);

    const int lane = threadIdx.x & 63;
    const int wave = threadIdx.x >> 6;
    const int wr = (wave >> 1) * 64;
    const int wc = (wave & 1) * 64;
    const int colb = lane & 15;
    const int rgrp = lane >> 4;

    #pragma unroll
    for (int m = 0; m < 4; ++m) {
        #pragma unroll
        for (int n = 0; n < 4; ++n) {
            #pragma unroll
            for (int j = 0; j < 4; ++j) {
                int gm = row0 + wr + m * 16 + rgrp * 4 + j;
                int gn = col0 + wc + n * 16 + colb;
                float v = acc[m][n][j] + bias[gn];
                int which = gn >> 10, c = gn & 1023, h = c >> 6, d = c & 63;
                int b = gm >> 12, l = gm & 4095, n0 = l >> 7, wq = l & 127;
                size_t wbase = (size_t)((b * HH + h) * NWIN + n0) * (WW * DH);
                if (which == 0)      qd [wbase + wq * 64 + d] = f2bf(v * 0.125f);
                else if (which == 1) kd [wbase + wq * 64 + d] = f2bf(v);
                else                 vtd[wbase + d * 128 + wq] = f2bf(v);
            }
        }
    }
}

// ---------------- Kernel 2: windowed causal attention ----------------
__global__ __launch_bounds__(256) void attn_kernel(const u16* __restrict__ q,
                                                   const u16* __restrict__ k,
                                                   const u16* __restrict__ vt,
                                                   u16* __restrict__ aout) {
    __shared__ u16 Ps[4][32 * 136];   // per-wave P tile, padded rows

    const int win = blockIdx.x;          // 0..2047
    const int b  = win >> 9;
    const int h  = (win >> 5) & 15;
    const int n0 = win & 31;
    const u16* qp = q  + (size_t)win * (WW * DH);
    const u16* kp = k  + (size_t)win * (WW * DH);
    const u16* vp = vt + (size_t)win * (WW * DH);

    const int lane = threadIdx.x & 63;
    const int wave = threadIdx.x >> 6;
    const int wrow = wave * 32;
    const int colb = lane & 15;
    const int kgrp = lane >> 4;
    const int rgrp = kgrp;

    f32x4 s[2][8];
    #pragma unroll
    for (int m = 0; m < 2; ++m)
        #pragma unroll
        for (int n = 0; n < 8; ++n)
            s[m][n] = (f32x4){0.f, 0.f, 0.f, 0.f};

    #pragma unroll
    for (int kk = 0; kk < 2; ++kk) {
        bf16x8 aq[2];
        #pragma unroll
        for (int m = 0; m < 2; ++m)
            aq[m] = *(const bf16x8*)&qp[(wrow + m * 16 + colb) * 64 + kk * 32 + kgrp * 8];
        #pragma unroll
        for (int n = 0; n < 8; ++n) {
            bf16x8 bk = *(const bf16x8*)&kp[(n * 16 + colb) * 64 + kk * 32 + kgrp * 8];
            s[0][n] = __builtin_amdgcn_mfma_f32_16x16x32_bf16(aq[0], bk, s[0][n], 0, 0, 0);
            s[1][n] = __builtin_amdgcn_mfma_f32_16x16x32_bf16(aq[1], bk, s[1][n], 0, 0, 0);
        }
    }

    #pragma unroll
    for (int m = 0; m < 2; ++m) {
        #pragma unroll
        for (int j = 0; j < 4; ++j) {
            int row = wrow + m * 16 + rgrp * 4 + j;
            float vals[8];
            float mx = -1e30f;
            #pragma unroll
            for (int n = 0; n < 8; ++n) {
                int col = n * 16 + colb;
                float v = s[m][n][j];
                if (col > row) v = -1e30f;
                vals[n] = v;
                mx = fmaxf(mx, v);
            }
            #pragma unroll
            for (int off = 1; off < 16; off <<= 1)
                mx = fmaxf(mx, __shfl_xor(mx, off, 64));
            float sum = 0.f;
            #pragma unroll
            for (int n = 0; n < 8; ++n) {
                float p = __expf(vals[n] - mx);
                vals[n] = p;
                sum += p;
            }
            #pragma unroll
            for (int off = 1; off < 16; off <<= 1)
                sum += __shfl_xor(sum, off, 64);
            float r = 1.0f / sum;
            #pragma unroll
            for (int n = 0; n < 8; ++n)
                Ps[wave][(m * 16 + rgrp * 4 + j) * 136 + n * 16 + colb] = f2bf(vals[n] * r);
        }
    }
    __syncthreads();

    f32x4 o[2][4];
    #pragma unroll
    for (int m = 0; m < 2; ++m)
        #pragma unroll
        for (int n = 0; n < 4; ++n)
            o[m][n] = (f32x4){0.f, 0.f, 0.f, 0.f};

    #pragma unroll
    for (int kk = 0; kk < 4; ++kk) {
        bf16x8 ap[2];
        #pragma unroll
        for (int m = 0; m < 2; ++m)
            ap[m] = *(const bf16x8*)&Ps[wave][(m * 16 + colb) * 136 + kk * 32 + kgrp * 8];
        #pragma unroll
        for (int n = 0; n < 4; ++n) {
            bf16x8 bv = *(const bf16x8*)&vp[(n * 16 + colb) * 128 + kk * 32 + kgrp * 8];
            o[0][n] = __builtin_amdgcn_mfma_f32_16x16x32_bf16(ap[0], bv, o[0][n], 0, 0, 0);
            o[1][n] = __builtin_amdgcn_mfma_f32_16x16x32_bf16(ap[1], bv, o[1][n], 0, 0, 0);
        }
    }

    #pragma unroll
    for (int m = 0; m < 2; ++m) {
        #pragma unroll
        for (int n = 0; n < 4; ++n) {
            #pragma unroll
            for (int j = 0; j < 4; ++j) {
                int row = wrow + m * 16 + rgrp * 4 + j;
                int l = n0 * 128 + row;
                int d = h * 64 + n * 16 + colb;
                aout[((size_t)(b * LL + l)) * DD + d] = f2bf(o[m][n][j]);
            }
        }
    }
}

// ---------------- Kernel 3: output projection GEMM + bias -> fp32 out ----------------
__global__ __launch_bounds__(256) void out_gemm_kernel(const u16* __restrict__ ab,
                                                       const u16* __restrict__ wb,
                                                       const float* __restrict__ bias,
                                                       float* __restrict__ out) {
    __shared__ u16 Als[128 * 32];
    __shared__ u16 Bls[128 * 32];
    f32x4 acc[4][4];
    const int row0 = blockIdx.y * 128;
    const int col0 = blockIdx.x * 128;
    gemm_tile_1024(ab, wb, row0, col0, Als, Bls, acc);

    const int lane = threadIdx.x & 63;
    const int wave = threadIdx.x >> 6;
    const int wr = (wave >> 1) * 64;
    const int wc = (wave & 1) * 64;
    const int colb = lane & 15;
    const int rgrp = lane >> 4;

    #pragma unroll
    for (int m = 0; m < 4; ++m) {
        #pragma unroll
        for (int n = 0; n < 4; ++n) {
            #pragma unroll
            for (int j = 0; j < 4; ++j) {
                int gm = row0 + wr + m * 16 + rgrp * 4 + j;
                int gn = col0 + wc + n * 16 + colb;
                out[(size_t)gm * DD + gn] = acc[m][n][j] + bias[gn];
            }
        }
    }
}

// ---------------- launch ----------------
extern "C" void kernel_launch(void* const* d_in, const int* in_sizes, int n_in,
                              void* d_out, int out_size, void* d_ws, size_t ws_size,
                              hipStream_t stream) {
    const float* x     = (const float*)d_in[0];
    const float* qkv_w = (const float*)d_in[1];
    const float* qkv_b = (const float*)d_in[2];
    const float* out_w = (const float*)d_in[3];
    const float* out_b = (const float*)d_in[4];
    float* out = (float*)d_out;

    char* ws = (char*)d_ws;
    u16* xb   = (u16*)(ws);                           // reused as attn_out
    u16* qwb  = (u16*)(ws + 33554432);
    u16* owb  = (u16*)(ws + 39845888);
    u16* qws  = (u16*)(ws + 41943040);
    u16* kws  = (u16*)(ws + 75497472);
    u16* vtws = (u16*)(ws + 109051904);

    cvt_f32_bf16<<<2048, 256, 0, stream>>>(x, xb, 16777216 / 8);
    cvt_f32_bf16<<<1536, 256, 0, stream>>>(qkv_w, qwb, 3145728 / 8);
    cvt_f32_bf16<<<512, 256, 0, stream>>>(out_w, owb, 1048576 / 8);

    qkv_gemm_kernel<<<dim3(NQKV / 128, MTOT / 128), 256, 0, stream>>>(xb, qwb, qkv_b, qws, kws, vtws);

    attn_kernel<<<BB * HH * NWIN, 256, 0, stream>>>(qws, kws, vtws, xb /* attn_out */);

    out_gemm_kernel<<<dim3(DD / 128, MTOT / 128), 256, 0, stream>>>(xb, owb, out_b, out);
}